// Round 5
// baseline (63.976 us; speedup 1.0000x reference)
//
#include <hip/hip_runtime.h>
#include <hip/hip_bf16.h>
#include <math.h>

#define BATCH 256
#define DM    768
#define REPR  1024
#define FF    3072

typedef __attribute__((ext_vector_type(8))) short bf16x8;
typedef __attribute__((ext_vector_type(4))) float f32x4;

__device__ __forceinline__ unsigned bf16rne(float f){
  union{float f; unsigned u;} x; x.f = f;
  return (x.u + 0x7FFFu + ((x.u >> 16) & 1u)) >> 16;
}
__device__ __forceinline__ unsigned pk2(float lo, float hi){
  return bf16rne(lo) | (bf16rne(hi) << 16);
}

// ---------------------------------------------------------------------------
// prep: transpose+convert W[K][N] f32 -> Wt[N][K] bf16 (64x64 LDS tiles),
// plus straight bf16 convert of im_repr.
// blocks: [0,192) Wv2, [192,768) W1, [768,1344) W2, [1344,1408) im.
// ---------------------------------------------------------------------------
__global__ __launch_bounds__(256)
void prep(const float* __restrict__ Wv2, const float* __restrict__ W1,
          const float* __restrict__ W2, const float* __restrict__ im,
          ushort* __restrict__ Wv2t, ushort* __restrict__ W1t,
          ushort* __restrict__ W2t, ushort* __restrict__ imbf)
{
  const int b = blockIdx.x, tid = threadIdx.x;
  if (b >= 1344) {                       // im convert: 64 blocks x 4096 elems
    const int base = (b - 1344) * 4096 + tid * 16;
    float4 v0 = *(const float4*)(im + base);
    float4 v1 = *(const float4*)(im + base + 4);
    float4 v2 = *(const float4*)(im + base + 8);
    float4 v3 = *(const float4*)(im + base + 12);
    uint4 o0 = { pk2(v0.x,v0.y), pk2(v0.z,v0.w), pk2(v1.x,v1.y), pk2(v1.z,v1.w) };
    uint4 o1 = { pk2(v2.x,v2.y), pk2(v2.z,v2.w), pk2(v3.x,v3.y), pk2(v3.z,v3.w) };
    *(uint4*)(imbf + base)     = o0;
    *(uint4*)(imbf + base + 8) = o1;
    return;
  }
  const float* src; ushort* dst; int K, N, rel;
  if (b < 192)      { src = Wv2; dst = Wv2t; K = REPR; N = DM; rel = b; }
  else if (b < 768) { src = W1;  dst = W1t;  K = DM;   N = FF; rel = b - 192; }
  else              { src = W2;  dst = W2t;  K = FF;   N = DM; rel = b - 768; }
  const int ntk = K >> 6;
  const int k0 = (rel % ntk) * 64, n0 = (rel / ntk) * 64;

  __shared__ float lds[64][65];          // +1 pad: phase-2 column reads 2-way (free)
  #pragma unroll
  for (int p = 0; p < 4; ++p) {          // load 64k x 64n f32, coalesced
    const int r = p * 16 + (tid >> 4), c4 = (tid & 15) * 4;
    float4 v = *(const float4*)(src + (size_t)(k0 + r) * N + n0 + c4);
    lds[r][c4] = v.x; lds[r][c4+1] = v.y; lds[r][c4+2] = v.z; lds[r][c4+3] = v.w;
  }
  __syncthreads();
  #pragma unroll
  for (int p = 0; p < 4; ++p) {          // store transposed bf16, coalesced
    const int nn = p * 16 + (tid >> 4), k4 = (tid & 15) * 4;
    uint2 o = { pk2(lds[k4][nn], lds[k4+1][nn]),
                pk2(lds[k4+2][nn], lds[k4+3][nn]) };
    *(uint2*)(dst + (size_t)(n0 + nn) * K + k0 + k4) = o;
  }
}

// ---------------------------------------------------------------------------
// gemm_rr: register-only GEMM, no LDS/barriers. A bf16 [M][lda], Bt bf16
// [N][K] pre-transposed. Block 32x64 (4 waves 2x2, wave 16x32). NSTEPS is
// compile-time -> full unroll, explicit prefetch distance PF=8 (24 loads in
// flight/wave); all buffer indices compile-time (rule #20: no scratch).
// Frag mapping (verified rounds 3-4): in row/col = lane&15, k-octet = lane>>4;
// out col = lane&15, row = (lane>>4)*4 + r.
// EPI 0: raw f32 partial -> outF[z][M][N]
// EPI 1: +bias, exact gelu -> bf16 outH
// EPI 2: +bias -> f32 outF AND bf16 outH   (G1: produces xf + xbf)
// ---------------------------------------------------------------------------
template<int NSTEPS, int EPI>
__global__ __launch_bounds__(256)
void gemm_rr(const ushort* __restrict__ Abf, const ushort* __restrict__ Bt,
             const float* __restrict__ bias, float* __restrict__ outF,
             ushort* __restrict__ outH, int N, int K, int lda)
{
  constexpr int PF = (NSTEPS < 8) ? NSTEPS : 8;

  const int gx = gridDim.x, gy = gridDim.y;
  const int nwg = gx * gy;
  int id = blockIdx.y * gx + blockIdx.x;
  if ((nwg & 7) == 0) id = (id & 7) * (nwg >> 3) + (id >> 3);  // XCD swizzle
  const int bx = id / gy, by = id % gy;

  const int lane = threadIdx.x & 63, wid = threadIdx.x >> 6;
  const int wr = wid >> 1, wc = wid & 1;
  const int arow = by * 32 + wr * 16 + (lane & 15);
  const int colb = bx * 64 + wc * 32;
  const int kq = (lane >> 4) * 8;
  const int kb = blockIdx.z * NSTEPS * 32;

  const ushort* ap  = Abf + (size_t)arow * lda + kb + kq;
  const ushort* bp0 = Bt + (size_t)(colb + 0  + (lane & 15)) * K + kb + kq;
  const ushort* bp1 = Bt + (size_t)(colb + 16 + (lane & 15)) * K + kb + kq;

  f32x4 acc0 = (f32x4)(0.0f), acc1 = (f32x4)(0.0f);

  union U { uint4 q; bf16x8 v; };
  U ab[PF], b0b[PF], b1b[PF];
  #pragma unroll
  for (int i = 0; i < PF; ++i) {         // fill the pipeline
    ab[i].q  = *(const uint4*)(ap  + i * 32);
    b0b[i].q = *(const uint4*)(bp0 + i * 32);
    b1b[i].q = *(const uint4*)(bp1 + i * 32);
  }
  #pragma unroll
  for (int t = 0; t < NSTEPS; ++t) {
    const int cur = t % PF;              // compile-time after unroll
    acc0 = __builtin_amdgcn_mfma_f32_16x16x32_bf16(ab[cur].v, b0b[cur].v, acc0, 0, 0, 0);
    acc1 = __builtin_amdgcn_mfma_f32_16x16x32_bf16(ab[cur].v, b1b[cur].v, acc1, 0, 0, 0);
    if (t + PF < NSTEPS) {               // refill slot just consumed
      ab[cur].q  = *(const uint4*)(ap  + (t + PF) * 32);
      b0b[cur].q = *(const uint4*)(bp0 + (t + PF) * 32);
      b1b[cur].q = *(const uint4*)(bp1 + (t + PF) * 32);
    }
  }

  const int crow = by * 32 + wr * 16 + (lane >> 4) * 4;
  #pragma unroll
  for (int nf = 0; nf < 2; ++nf) {
    const int c = colb + nf * 16 + (lane & 15);
    const f32x4 a = nf ? acc1 : acc0;
    #pragma unroll
    for (int r = 0; r < 4; ++r) {
      const int row = crow + r;
      if (EPI == 0) {
        outF[(size_t)blockIdx.z * BATCH * N + (size_t)row * N + c] = a[r];
      } else if (EPI == 1) {
        float v = a[r] + bias[c];
        v = 0.5f * v * (1.0f + erff(v * 0.70710678118654752f));
        outH[(size_t)row * N + c] = (ushort)bf16rne(v);
      } else {
        float v = a[r] + bias[c];
        outF[(size_t)row * N + c] = v;
        outH[(size_t)row * N + c] = (ushort)bf16rne(v);
      }
    }
  }
}

// ---------------------------------------------------------------------------
// ln_final: y = xf + sum_{z<4} P3[z] + b2, then LayerNorm -> out. 1 block/row.
// ---------------------------------------------------------------------------
__global__ __launch_bounds__(256)
void ln_final(const float* __restrict__ P3, const float* __restrict__ xf,
              const float* __restrict__ b2, const float* __restrict__ g,
              const float* __restrict__ be, float* __restrict__ out)
{
  const int row = blockIdx.x, tid = threadIdx.x;
  const int lane = tid & 63, wave = tid >> 6;

  float v[3];
  #pragma unroll
  for (int i = 0; i < 3; ++i) {
    const int c = tid + i * 256;
    float s = xf[(size_t)row * DM + c] + b2[c];
    #pragma unroll
    for (int z = 0; z < 4; ++z) s += P3[((size_t)z * BATCH + row) * DM + c];
    v[i] = s;
  }

  __shared__ float red[4];
  float s = v[0] + v[1] + v[2];
  #pragma unroll
  for (int o = 32; o > 0; o >>= 1) s += __shfl_down(s, o);
  if (lane == 0) red[wave] = s;
  __syncthreads();
  const float mu = (red[0] + red[1] + red[2] + red[3]) * (1.0f / 768.0f);
  __syncthreads();
  const float d0 = v[0] - mu, d1 = v[1] - mu, d2 = v[2] - mu;
  float q = d0*d0 + d1*d1 + d2*d2;
  #pragma unroll
  for (int o = 32; o > 0; o >>= 1) q += __shfl_down(q, o);
  if (lane == 0) red[wave] = q;
  __syncthreads();
  const float var = (red[0] + red[1] + red[2] + red[3]) * (1.0f / 768.0f);
  const float inv = rsqrtf(var + 1e-12f);

  float* o = out + (size_t)row * DM;
  o[tid      ] = d0 * inv * g[tid      ] + be[tid      ];
  o[tid + 256] = d1 * inv * g[tid + 256] + be[tid + 256];
  o[tid + 512] = d2 * inv * g[tid + 512] + be[tid + 512];
}

// ---------------------------------------------------------------------------
// prep -> G1 (no split, epi writes xf+xbf) -> G2 -> G3 (split-4) -> LN.
// 5 kernels. ws usage ~17 MB (ws ~346 MB per fill counters).
// ---------------------------------------------------------------------------
extern "C" void kernel_launch(void* const* d_in, const int* in_sizes, int n_in,
                              void* d_out, int out_size, void* d_ws, size_t ws_size,
                              hipStream_t stream)
{
  const float* im  = (const float*)d_in[0];
  const float* Wv2 = (const float*)d_in[12];
  const float* bv2 = (const float*)d_in[13];
  const float* W1  = (const float*)d_in[14];
  const float* b1  = (const float*)d_in[15];
  const float* W2  = (const float*)d_in[16];
  const float* b2  = (const float*)d_in[17];
  const float* g   = (const float*)d_in[18];
  const float* be  = (const float*)d_in[19];
  float* out = (float*)d_out;

  char* w = (char*)d_ws;
  ushort* Wv2t = (ushort*)(w);               // 768*1024*2  = 1572864
  ushort* W1t  = (ushort*)(w + 1572864);     // 3072*768*2  = 4718592
  ushort* W2t  = (ushort*)(w + 6291456);     // 768*3072*2  = 4718592
  ushort* imbf = (ushort*)(w + 11010048);    // 256*1024*2  = 524288
  ushort* xbf  = (ushort*)(w + 11534336);    // 256*768*2   = 393216
  ushort* tbf  = (ushort*)(w + 11927552);    // 256*3072*2  = 1572864
  float*  xf   = (float*) (w + 13500416);    // 256*768*4   = 786432
  float*  P3   = (float*) (w + 14286848);    // 4*256*768*4 = 3145728 -> 17.4MB

  // T: transpose/convert weights + im
  prep<<<1408, 256, 0, stream>>>(Wv2, W1, W2, im, Wv2t, W1t, W2t, imbf);
  // G1: x = im @ Wv2 + bv2 -> xf (f32) + xbf (bf16)   (M=256,N=768,K=1024)
  gemm_rr<32, 2><<<dim3(12, 8, 1), 256, 0, stream>>>(imbf, Wv2t, bv2, xf, xbf,
                                                     DM, REPR, REPR);
  // G2: tbf = bf16(gelu(x @ W1 + b1))                 (M=256,N=3072,K=768)
  gemm_rr<24, 1><<<dim3(48, 8, 1), 256, 0, stream>>>(xbf, W1t, b1, nullptr, tbf,
                                                     FF, DM, DM);
  // G3: P3[z] = (t @ W2) K-slices                     (M=256,N=768,K=3072, split-4)
  gemm_rr<24, 0><<<dim3(12, 8, 4), 256, 0, stream>>>(tbf, W2t, nullptr, P3, nullptr,
                                                     DM, FF, FF);
  // LN(xf + sum P3 + b2) -> out
  ln_final<<<BATCH, 256, 0, stream>>>(P3, xf, b2, g, be, out);
}